// Round 8
// baseline (197.955 us; speedup 1.0000x reference)
//
#include <hip/hip_runtime.h>

#define NPTS   65536
#define TOTAL  (2 * NPTS)
#define NUNITS 1024            // units of 128 points

typedef __attribute__((ext_vector_type(8)))  short short8;
typedef __attribute__((ext_vector_type(16))) float float16;
union F8 { uint4 u; short8 s; };

// ws byte offsets
#define WS_STRIPE 0                    // fp32[1024][64] per-block max, plain stores (no init needed)
#define WS_T1A    262144               // bf16[TOTAL][32] f_nei, 64B rows

__device__ __forceinline__ unsigned short f2bf(float x) {
    unsigned u = __float_as_uint(x);
    return (unsigned short)((u + 0x7FFFu + ((u >> 16) & 1u)) >> 16);
}
__device__ __forceinline__ unsigned pk2(float a, float b) {
    return (unsigned)f2bf(a) | ((unsigned)f2bf(b) << 16);
}
__device__ __forceinline__ float relu(float x) { return x > 0.f ? x : 0.f; }
__device__ __forceinline__ uint4 pk8(const float* e) {
    uint4 u;
    u.x = pk2(e[0], e[1]); u.y = pk2(e[2], e[3]);
    u.z = pk2(e[4], e[5]); u.w = pk2(e[6], e[7]);
    return u;
}
__device__ __forceinline__ float16 zero16() {
    float16 z;
#pragma unroll
    for (int i = 0; i < 16; i++) z[i] = 0.f;
    return z;
}

// ===== Kernel A: tnet trunk + block max (plain-store slot) + f_nei GEMM =====
__global__ __launch_bounds__(256) void kA(
    const float* __restrict__ feature, const float* __restrict__ xyz,
    const float* __restrict__ tW1, const float* __restrict__ ts1, const float* __restrict__ tb1,
    const float* __restrict__ tW2, const float* __restrict__ ts2, const float* __restrict__ tb2,
    const float* __restrict__ W2,  const float* __restrict__ s2,  const float* __restrict__ b2,
    char* ws)
{
    __shared__ float red[4][64];
    float* stripe       = (float*)(ws + WS_STRIPE);
    unsigned short* t1a = (unsigned short*)(ws + WS_T1A);
    const int lane = threadIdx.x & 63, wv = threadIdx.x >> 6;
    const int col = lane & 31, h = lane >> 5;
    const float16 z = zero16();
    const int u = blockIdx.x;                   // 1024 blocks, 128 pts each
    const int b = u >> 9;
    float e[8];
    // trunk weights: tW1*ts1 (VALU side), tW2^T*ts2 (B-frags)
    float aw0[8], aw1[8], aw2[8], bb[8];
#pragma unroll
    for (int j = 0; j < 8; j++) {
        int k = 8 * h + j; float s = ts1[k];
        aw0[j] = tW1[k] * s; aw1[j] = tW1[16 + k] * s; aw2[j] = tW1[32 + k] * s;
        bb[j] = tb1[k];
    }
    F8 bf0, bf1;
#pragma unroll
    for (int j = 0; j < 8; j++) e[j] = tW2[(8 * h + j) * 64 + col] * ts2[col];
    bf0.u = pk8(e);
#pragma unroll
    for (int j = 0; j < 8; j++) e[j] = tW2[(8 * h + j) * 64 + 32 + col] * ts2[32 + col];
    bf1.u = pk8(e);
    // f_nei weights: W2^T folded as A-frags
    F8 a0, a1;
    float sc2 = s2[col];
#pragma unroll
    for (int j = 0; j < 8; j++) e[j] = W2[(8 * h + j) * 32 + col] * sc2;
    a0.u = pk8(e);
#pragma unroll
    for (int j = 0; j < 8; j++) e[j] = W2[(16 + 8 * h + j) * 32 + col] * sc2;
    a1.u = pk8(e);
    float b2v[16];
#pragma unroll
    for (int r = 0; r < 16; r++) b2v[r] = b2[(r & 3) + 8 * (r >> 2) + 4 * h];

    int base = u * 128 + wv * 32;
    // trunk + max
    const float* xp = xyz + (size_t)(base + col) * 3;
    float x0 = xp[0], x1 = xp[1], x2 = xp[2];
    float hv[8];
#pragma unroll
    for (int j = 0; j < 8; j++)
        hv[j] = relu(x0 * aw0[j] + x1 * aw1[j] + x2 * aw2[j] + bb[j]);
    F8 af; af.u = pk8(hv);
    float16 c0 = __builtin_amdgcn_mfma_f32_32x32x16_bf16(af.s, bf0.s, z, 0, 0, 0);
    float16 c1 = __builtin_amdgcn_mfma_f32_32x32x16_bf16(af.s, bf1.s, z, 0, 0, 0);
    float v0 = c0[0], v1 = c1[0];
#pragma unroll
    for (int i = 1; i < 16; i++) { v0 = fmaxf(v0, c0[i]); v1 = fmaxf(v1, c1[i]); }
    v0 = fmaxf(v0, __shfl_xor(v0, 32));
    v1 = fmaxf(v1, __shfl_xor(v1, 32));
    if (h == 0) { red[wv][col] = v0; red[wv][32 + col] = v1; }
    __syncthreads();
    if (threadIdx.x < 64) {
        int c = threadIdx.x;
        float m = fmaxf(fmaxf(red[0][c], red[1][c]), fmaxf(red[2][c], red[3][c]));
        // bias/relu before cross-block max is valid: relu(x+tb) monotone in x
        stripe[u * 64 + c] = relu(m + tb2[c]);  // plain store; every slot owned by its block
    }
    // f_nei GEMM
    int pt = base + col;
    const float* fb = feature + (size_t)b * 32 * NPTS + (pt & (NPTS - 1));
    float v[8];
    F8 f0, f1;
#pragma unroll
    for (int j = 0; j < 8; j++) v[j] = fb[(size_t)(8 * h + j) * NPTS];
    f0.u = pk8(v);
#pragma unroll
    for (int j = 0; j < 8; j++) v[j] = fb[(size_t)(16 + 8 * h + j) * NPTS];
    f1.u = pk8(v);
    float16 acc = z;
    acc = __builtin_amdgcn_mfma_f32_32x32x16_bf16(a0.s, f0.s, acc, 0, 0, 0);
    acc = __builtin_amdgcn_mfma_f32_32x32x16_bf16(a1.s, f1.s, acc, 0, 0, 0);
#pragma unroll
    for (int q = 0; q < 4; q++) {
        int r = 4 * q;
        uint2 uu;
        uu.x = pk2(relu(acc[r] + b2v[r]), relu(acc[r + 1] + b2v[r + 1]));
        uu.y = pk2(relu(acc[r + 2] + b2v[r + 2]), relu(acc[r + 3] + b2v[r + 3]));
        *(uint2*)(t1a + (size_t)pt * 32 + 8 * q + 4 * h) = uu;
    }
}

// ===== Kernel B: tnet head + gather GEMM (inline f_xyz) + output GEMM =====
__global__ __launch_bounds__(256) void kB(
    const float* __restrict__ feature, const float* __restrict__ xyz,
    const int* __restrict__ nidx,
    const float* __restrict__ tW3, const float* __restrict__ ts3, const float* __restrict__ tb3,
    const float* __restrict__ tW4, const float* __restrict__ tb4,
    const float* __restrict__ W1,  const float* __restrict__ s1, const float* __restrict__ b1,
    const float* __restrict__ W3,  const float* __restrict__ s3, const float* __restrict__ b3,
    const float* __restrict__ W4,  const float* __restrict__ s4, const float* __restrict__ b4,
    char* ws, float* __restrict__ out)
{
    __shared__ float redh[4][64];
    __shared__ float Tsh[9];
    __shared__ unsigned short mld[128 * 36];
    const float* stripe       = (const float*)(ws + WS_STRIPE);
    const unsigned short* t1a = (const unsigned short*)(ws + WS_T1A);
    const int lane = threadIdx.x & 63, wv = threadIdx.x >> 6;
    const int col = lane & 31, h = lane >> 5;
    const float16 z = zero16();

    // XCD-batch affinity: blk&7 is XCD slot; slot>=4 -> batch 1
    int slot = blockIdx.x & 7, batch = slot >> 2;
    int grp = (blockIdx.x >> 3) * 4 + (slot & 3);   // [0, 512) within batch
    int base = (batch * 512 + grp) * 128;

    // preload neighbor indices early (independent, in flight through head reduce)
    int idxs[16];
#pragma unroll
    for (int it = 0; it < 16; it++)
        idxs[it] = nidx[(base + 2 * (wv * 16 + it)) * 16 + col];

    // ---- tnet head: block-parallel reduce of 512 per-block slots -> butterfly -> T
    {
        int c = threadIdx.x & 63, part = threadIdx.x >> 6;
        const float* sp = stripe + (size_t)(batch * 512 + part * 128) * 64 + c;
        float hm = 0.f;                         // values are relu'd >= 0
#pragma unroll 8
        for (int s = 0; s < 128; s++) hm = fmaxf(hm, sp[s * 64]);
        redh[part][c] = hm;
    }
    __syncthreads();
    if (wv == 0) {
        float hm = fmaxf(fmaxf(redh[0][lane], redh[1][lane]),
                         fmaxf(redh[2][lane], redh[3][lane]));
        float v[16];                            // lane i contributes hm_i * tW3[i][:]
        const float4* trow = (const float4*)(tW3 + lane * 16);
#pragma unroll
        for (int q = 0; q < 4; q++) {
            float4 t4 = trow[q];
            v[4 * q + 0] = hm * t4.x; v[4 * q + 1] = hm * t4.y;
            v[4 * q + 2] = hm * t4.z; v[4 * q + 3] = hm * t4.w;
        }
#pragma unroll
        for (int off = 1; off < 64; off <<= 1) {
#pragma unroll
            for (int c = 0; c < 16; c++) v[c] += __shfl_xor(v[c], off);
        }
        float T[9];
#pragma unroll
        for (int j = 0; j < 9; j++) T[j] = tb4[j];
#pragma unroll
        for (int c = 0; c < 16; c++) {
            float h3 = relu(v[c] * ts3[c] + tb3[c]);
#pragma unroll
            for (int j = 0; j < 9; j++) T[j] += h3 * tW4[c * 9 + j];
        }
        T[0] += 1.f; T[4] += 1.f; T[8] += 1.f;
        if (lane < 9) Tsh[lane] = T[lane];
    }

    // ---- weights (overlap with head-reduce latency) ----
    float e[8];
    F8 w0, w1, w2, zf;
    zf.u.x = zf.u.y = zf.u.z = zf.u.w = 0u;
    float sc3 = s3[col];
#pragma unroll
    for (int j = 0; j < 8; j++) e[j] = W3[(8 * h + j) * 32 + col] * sc3;
    w0.u = pk8(e);
#pragma unroll
    for (int j = 0; j < 8; j++) e[j] = W3[(16 + 8 * h + j) * 32 + col] * sc3;
    w1.u = pk8(e);
    w2 = zf;
    if (h == 0) {
        float e2[8] = {0.f, 0.f, 0.f, 0.f, 0.f, 0.f, 0.f, 0.f};
#pragma unroll
        for (int j = 0; j < 3; j++) e2[j] = W3[(32 + j) * 32 + col] * sc3;
        w2.u = pk8(e2);
    }
    float b3v = b3[col];
    F8 aw[4];
    float sc4 = s4[col];
#pragma unroll
    for (int t = 0; t < 4; t++) {
#pragma unroll
        for (int j = 0; j < 8; j++) e[j] = W4[(16 * t + 8 * h + j) * 32 + col] * sc4;
        aw[t].u = pk8(e);
    }
    float b4v[16];
#pragma unroll
    for (int r = 0; r < 16; r++) b4v[r] = b4[(r & 3) + 8 * (r >> 2) + 4 * h];
    float W1f[9], b1v[3];
#pragma unroll
    for (int j = 0; j < 9; j++) W1f[j] = W1[j] * s1[j % 3];
#pragma unroll
    for (int j = 0; j < 3; j++) b1v[j] = b1[j];

    // ---- output-GEMM feat fragments from global fp32 (issued early, used last)
    int p_loc = wv * 32 + col;
    int p = base + p_loc;
    {
        const float* fb = feature + (size_t)batch * 32 * NPTS + (p & (NPTS - 1));
        float v[8];
#pragma unroll
        for (int j = 0; j < 8; j++) v[j] = fb[(size_t)(8 * h + j) * NPTS];
        e[0] = v[0]; // silence unused warnings pattern; real pack below
        F8 xf0, xf1;
        xf0.u = pk8(v);
#pragma unroll
        for (int j = 0; j < 8; j++) v[j] = fb[(size_t)(16 + 8 * h + j) * NPTS];
        xf1.u = pk8(v);
        // stash in e-free registers via union reuse
        w2 = w2; // no-op
        // keep xf0/xf1 alive to the end:
        __syncthreads();                         // T ready before gather loop

        float T[9];
#pragma unroll
        for (int j = 0; j < 9; j++) T[j] = Tsh[j];

        // ---- gather loop: register double-buffered; a2 (f_xyz) computed inline on h=0
        F8 na0, na1;
        float nx0 = 0.f, nx1 = 0.f, nx2 = 0.f;
        {
            size_t row = ((size_t)batch << 16) + (unsigned)idxs[0];
            const unsigned short* ap = t1a + row * 32;
            na0.u = *(const uint4*)(ap + 8 * h);
            na1.u = *(const uint4*)(ap + 16 + 8 * h);
            if (h == 0) {
                const float* nxp = xyz + row * 3;
                nx0 = nxp[0]; nx1 = nxp[1]; nx2 = nxp[2];
            }
        }
        for (int it = 0; it < 16; it++) {
            F8 ca0 = na0, ca1 = na1;
            float cx0 = nx0, cx1 = nx1, cx2 = nx2;
            if (it < 15) {
                size_t row = ((size_t)batch << 16) + (unsigned)idxs[it + 1];
                const unsigned short* ap = t1a + row * 32;
                na0.u = *(const uint4*)(ap + 8 * h);
                na1.u = *(const uint4*)(ap + 16 + 8 * h);
                if (h == 0) {
                    const float* nxp = xyz + row * 3;
                    nx0 = nxp[0]; nx1 = nxp[1]; nx2 = nxp[2];
                }
            }
            F8 ca2 = zf;
            if (h == 0) {                        // f_xyz inline: ~20 VALU on half the lanes
                float q0 = cx0 * T[0] + cx1 * T[3] + cx2 * T[6];
                float q1 = cx0 * T[1] + cx1 * T[4] + cx2 * T[7];
                float q2 = cx0 * T[2] + cx1 * T[5] + cx2 * T[8];
                float r0 = relu(q0 * W1f[0] + q1 * W1f[3] + q2 * W1f[6] + b1v[0]);
                float r1 = relu(q0 * W1f[1] + q1 * W1f[4] + q2 * W1f[7] + b1v[1]);
                float r2 = relu(q0 * W1f[2] + q1 * W1f[5] + q2 * W1f[8] + b1v[2]);
                ca2.u.x = pk2(r0, r1); ca2.u.y = pk2(r2, 0.f);
            }
            float16 acc = z;
            acc = __builtin_amdgcn_mfma_f32_32x32x16_bf16(ca0.s, w0.s, acc, 0, 0, 0);
            acc = __builtin_amdgcn_mfma_f32_32x32x16_bf16(ca1.s, w1.s, acc, 0, 0, 0);
            acc = __builtin_amdgcn_mfma_f32_32x32x16_bf16(ca2.s, w2.s, acc, 0, 0, 0);
            float vA = acc[0], vB = acc[8];
#pragma unroll
            for (int r = 1; r < 8; r++) { vA = fmaxf(vA, acc[r]); vB = fmaxf(vB, acc[8 + r]); }
            vA = fmaxf(vA, __shfl_xor(vA, 32));
            vB = fmaxf(vB, __shfl_xor(vB, 32));
            vA = relu(vA + b3v);
            vB = relu(vB + b3v);
            float val = h ? vB : vA;
            int pi = wv * 16 + it;
            mld[(2 * pi + h) * 36 + col] = f2bf(val);   // same-wave produce/consume
        }

        // ---- output GEMM: m from LDS (same wave), feat frags from above
        const unsigned short* mp = mld + p_loc * 36;
        uint2 q0 = *(const uint2*)(mp + 8 * h);
        uint2 q1 = *(const uint2*)(mp + 8 * h + 4);
        uint2 q2 = *(const uint2*)(mp + 16 + 8 * h);
        uint2 q3 = *(const uint2*)(mp + 16 + 8 * h + 4);
        F8 xm0, xm1;
        xm0.u.x = q0.x; xm0.u.y = q0.y; xm0.u.z = q1.x; xm0.u.w = q1.y;
        xm1.u.x = q2.x; xm1.u.y = q2.y; xm1.u.z = q3.x; xm1.u.w = q3.y;
        float16 acc = z;
        acc = __builtin_amdgcn_mfma_f32_32x32x16_bf16(aw[0].s, xf0.s, acc, 0, 0, 0);
        acc = __builtin_amdgcn_mfma_f32_32x32x16_bf16(aw[1].s, xf1.s, acc, 0, 0, 0);
        acc = __builtin_amdgcn_mfma_f32_32x32x16_bf16(aw[2].s, xm0.s, acc, 0, 0, 0);
        acc = __builtin_amdgcn_mfma_f32_32x32x16_bf16(aw[3].s, xm1.s, acc, 0, 0, 0);
        float* ob = out + (size_t)(batch * 32) * NPTS + (p & (NPTS - 1));
#pragma unroll
        for (int r = 0; r < 16; r++) {
            int o = (r & 3) + 8 * (r >> 2) + 4 * h;
            ob[(size_t)o * NPTS] = relu(acc[r] + b4v[r]);
        }
    }
}

extern "C" void kernel_launch(void* const* d_in, const int* in_sizes, int n_in,
                              void* d_out, int out_size, void* d_ws, size_t ws_size,
                              hipStream_t stream)
{
    const float* feature = (const float*)d_in[0];
    const float* xyz     = (const float*)d_in[1];
    const int*   nidx    = (const int*)d_in[2];
    const float* tW1 = (const float*)d_in[3];
    const float* ts1 = (const float*)d_in[4];
    const float* tb1 = (const float*)d_in[5];
    const float* tW2 = (const float*)d_in[6];
    const float* ts2 = (const float*)d_in[7];
    const float* tb2 = (const float*)d_in[8];
    const float* tW3 = (const float*)d_in[9];
    const float* ts3 = (const float*)d_in[10];
    const float* tb3 = (const float*)d_in[11];
    const float* tW4 = (const float*)d_in[12];
    const float* tb4 = (const float*)d_in[13];
    const float* W1  = (const float*)d_in[14];
    const float* s1  = (const float*)d_in[15];
    const float* b1  = (const float*)d_in[16];
    const float* W2  = (const float*)d_in[17];
    const float* s2  = (const float*)d_in[18];
    const float* b2  = (const float*)d_in[19];
    const float* W3  = (const float*)d_in[20];
    const float* s3  = (const float*)d_in[21];
    const float* b3  = (const float*)d_in[22];
    const float* W4  = (const float*)d_in[23];
    const float* s4  = (const float*)d_in[24];
    const float* b4  = (const float*)d_in[25];
    (void)in_sizes; (void)n_in; (void)out_size; (void)ws_size;

    char* wsp = (char*)d_ws;
    float* outp = (float*)d_out;

    kA<<<NUNITS, 256, 0, stream>>>(feature, xyz, tW1, ts1, tb1, tW2, ts2, tb2,
                                   W2, s2, b2, wsp);
    kB<<<NUNITS, 256, 0, stream>>>(feature, xyz, nidx, tW3, ts3, tb3, tW4, tb4,
                                   W1, s1, b1, W3, s3, b3, W4, s4, b4, wsp, outp);
}

// Round 9
// 177.548 us; speedup vs baseline: 1.1149x; 1.1149x over previous
//
#include <hip/hip_runtime.h>

#define NPTS   65536
#define TOTAL  (2 * NPTS)

typedef __attribute__((ext_vector_type(8)))  short short8;
typedef __attribute__((ext_vector_type(16))) float float16;
union F8 { uint4 u; short8 s; };

// ws byte offsets
#define WS_STRIPE 0                    // fp32[1024][64] per-block max, plain stores (no init needed)
#define WS_TG     262144               // fp32[2][16]  head transform T per batch
#define WS_T1A    262400               // bf16[TOTAL][32] f_nei, 64B rows
#define WS_T2     (262400 + TOTAL * 64) // bf16[TOTAL][32] feat, 64B rows

__device__ __forceinline__ unsigned short f2bf(float x) {
    unsigned u = __float_as_uint(x);
    return (unsigned short)((u + 0x7FFFu + ((u >> 16) & 1u)) >> 16);
}
__device__ __forceinline__ unsigned pk2(float a, float b) {
    return (unsigned)f2bf(a) | ((unsigned)f2bf(b) << 16);
}
__device__ __forceinline__ float relu(float x) { return x > 0.f ? x : 0.f; }
__device__ __forceinline__ uint4 pk8(const float* e) {
    uint4 u;
    u.x = pk2(e[0], e[1]); u.y = pk2(e[2], e[3]);
    u.z = pk2(e[4], e[5]); u.w = pk2(e[6], e[7]);
    return u;
}
__device__ __forceinline__ float16 zero16() {
    float16 z;
#pragma unroll
    for (int i = 0; i < 16; i++) z[i] = 0.f;
    return z;
}

// ===== Kernel A: tnet trunk + block max slot + f_nei GEMM + feat bf16 copy =====
__global__ __launch_bounds__(256) void kA(
    const float* __restrict__ feature, const float* __restrict__ xyz,
    const float* __restrict__ tW1, const float* __restrict__ ts1, const float* __restrict__ tb1,
    const float* __restrict__ tW2, const float* __restrict__ ts2, const float* __restrict__ tb2,
    const float* __restrict__ W2,  const float* __restrict__ s2,  const float* __restrict__ b2,
    char* ws)
{
    __shared__ float red[4][64];
    float* stripe       = (float*)(ws + WS_STRIPE);
    unsigned short* t1a = (unsigned short*)(ws + WS_T1A);
    unsigned short* t2  = (unsigned short*)(ws + WS_T2);
    const int lane = threadIdx.x & 63, wv = threadIdx.x >> 6;
    const int col = lane & 31, h = lane >> 5;
    const float16 z = zero16();
    const int u = blockIdx.x;                   // 1024 blocks, 128 pts each
    const int b = u >> 9;
    float e[8];
    float aw0[8], aw1[8], aw2[8], bb[8];
#pragma unroll
    for (int j = 0; j < 8; j++) {
        int k = 8 * h + j; float s = ts1[k];
        aw0[j] = tW1[k] * s; aw1[j] = tW1[16 + k] * s; aw2[j] = tW1[32 + k] * s;
        bb[j] = tb1[k];
    }
    F8 bf0, bf1;
#pragma unroll
    for (int j = 0; j < 8; j++) e[j] = tW2[(8 * h + j) * 64 + col] * ts2[col];
    bf0.u = pk8(e);
#pragma unroll
    for (int j = 0; j < 8; j++) e[j] = tW2[(8 * h + j) * 64 + 32 + col] * ts2[32 + col];
    bf1.u = pk8(e);
    F8 a0, a1;
    float sc2 = s2[col];
#pragma unroll
    for (int j = 0; j < 8; j++) e[j] = W2[(8 * h + j) * 32 + col] * sc2;
    a0.u = pk8(e);
#pragma unroll
    for (int j = 0; j < 8; j++) e[j] = W2[(16 + 8 * h + j) * 32 + col] * sc2;
    a1.u = pk8(e);
    float b2v[16];
#pragma unroll
    for (int r = 0; r < 16; r++) b2v[r] = b2[(r & 3) + 8 * (r >> 2) + 4 * h];

    int base = u * 128 + wv * 32;
    const float* xp = xyz + (size_t)(base + col) * 3;
    float x0 = xp[0], x1 = xp[1], x2 = xp[2];
    float hv[8];
#pragma unroll
    for (int j = 0; j < 8; j++)
        hv[j] = relu(x0 * aw0[j] + x1 * aw1[j] + x2 * aw2[j] + bb[j]);
    F8 af; af.u = pk8(hv);
    float16 c0 = __builtin_amdgcn_mfma_f32_32x32x16_bf16(af.s, bf0.s, z, 0, 0, 0);
    float16 c1 = __builtin_amdgcn_mfma_f32_32x32x16_bf16(af.s, bf1.s, z, 0, 0, 0);
    float v0 = c0[0], v1 = c1[0];
#pragma unroll
    for (int i = 1; i < 16; i++) { v0 = fmaxf(v0, c0[i]); v1 = fmaxf(v1, c1[i]); }
    v0 = fmaxf(v0, __shfl_xor(v0, 32));
    v1 = fmaxf(v1, __shfl_xor(v1, 32));
    if (h == 0) { red[wv][col] = v0; red[wv][32 + col] = v1; }
    __syncthreads();
    if (threadIdx.x < 64) {
        int c = threadIdx.x;
        float m = fmaxf(fmaxf(red[0][c], red[1][c]), fmaxf(red[2][c], red[3][c]));
        stripe[u * 64 + c] = relu(m + tb2[c]);  // relu(x+tb) monotone: valid before global max
    }
    // f_nei GEMM + feat bf16 copy
    int pt = base + col;
    const float* fb = feature + (size_t)b * 32 * NPTS + (pt & (NPTS - 1));
    float v[8];
    F8 f0, f1;
#pragma unroll
    for (int j = 0; j < 8; j++) v[j] = fb[(size_t)(8 * h + j) * NPTS];
    f0.u = pk8(v);
#pragma unroll
    for (int j = 0; j < 8; j++) v[j] = fb[(size_t)(16 + 8 * h + j) * NPTS];
    f1.u = pk8(v);
    *(uint4*)(t2 + (size_t)pt * 32 + 8 * h) = f0.u;
    *(uint4*)(t2 + (size_t)pt * 32 + 16 + 8 * h) = f1.u;
    float16 acc = z;
    acc = __builtin_amdgcn_mfma_f32_32x32x16_bf16(a0.s, f0.s, acc, 0, 0, 0);
    acc = __builtin_amdgcn_mfma_f32_32x32x16_bf16(a1.s, f1.s, acc, 0, 0, 0);
#pragma unroll
    for (int q = 0; q < 4; q++) {
        int r = 4 * q;
        uint2 uu;
        uu.x = pk2(relu(acc[r] + b2v[r]), relu(acc[r + 1] + b2v[r + 1]));
        uu.y = pk2(relu(acc[r + 2] + b2v[r + 2]), relu(acc[r + 3] + b2v[r + 3]));
        *(uint2*)(t1a + (size_t)pt * 32 + 8 * q + 4 * h) = uu;
    }
}

// ===== Kernel H: reduce 512 slots -> tnet head -> Tg[batch][9] (one block/batch) ==
__global__ __launch_bounds__(256) void kH(
    const float* __restrict__ tW3, const float* __restrict__ ts3, const float* __restrict__ tb3,
    const float* __restrict__ tW4, const float* __restrict__ tb4, char* ws)
{
    __shared__ float redh[4][64];
    const float* stripe = (const float*)(ws + WS_STRIPE);
    float* Tg           = (float*)(ws + WS_TG);
    const int batch = blockIdx.x;
    const int lane = threadIdx.x & 63, wv = threadIdx.x >> 6;
    {
        const float* sp = stripe + (size_t)(batch * 512 + wv * 128) * 64 + lane;
        float hm = 0.f;                         // values relu'd >= 0
#pragma unroll 8
        for (int s = 0; s < 128; s++) hm = fmaxf(hm, sp[s * 64]);
        redh[wv][lane] = hm;
    }
    __syncthreads();
    if (wv == 0) {
        float hm = fmaxf(fmaxf(redh[0][lane], redh[1][lane]),
                         fmaxf(redh[2][lane], redh[3][lane]));
        float v[16];                            // lane i contributes hm_i * tW3[i][:]
        const float4* trow = (const float4*)(tW3 + lane * 16);
#pragma unroll
        for (int q = 0; q < 4; q++) {
            float4 t4 = trow[q];
            v[4 * q + 0] = hm * t4.x; v[4 * q + 1] = hm * t4.y;
            v[4 * q + 2] = hm * t4.z; v[4 * q + 3] = hm * t4.w;
        }
#pragma unroll
        for (int off = 1; off < 64; off <<= 1) {
#pragma unroll
            for (int c = 0; c < 16; c++) v[c] += __shfl_xor(v[c], off);
        }
        float T[9];
#pragma unroll
        for (int j = 0; j < 9; j++) T[j] = tb4[j];
#pragma unroll
        for (int c = 0; c < 16; c++) {
            float h3 = relu(v[c] * ts3[c] + tb3[c]);
#pragma unroll
            for (int j = 0; j < 9; j++) T[j] += h3 * tW4[c * 9 + j];
        }
        T[0] += 1.f; T[4] += 1.f; T[8] += 1.f;
        if (lane < 9) Tg[batch * 16 + lane] = T[lane];
    }
}

// ===== Kernel B: gather GEMM (inline f_xyz) + max-over-K + output GEMM =====
__global__ __launch_bounds__(256) void kB(
    const float* __restrict__ xyz, const int* __restrict__ nidx,
    const float* __restrict__ W1,  const float* __restrict__ s1, const float* __restrict__ b1,
    const float* __restrict__ W3,  const float* __restrict__ s3, const float* __restrict__ b3,
    const float* __restrict__ W4,  const float* __restrict__ s4, const float* __restrict__ b4,
    char* ws, float* __restrict__ out)
{
    __shared__ unsigned short mld[64 * 36];
    const float* Tg           = (const float*)(ws + WS_TG);
    const unsigned short* t1a = (const unsigned short*)(ws + WS_T1A);
    const unsigned short* t2  = (const unsigned short*)(ws + WS_T2);
    const int lane = threadIdx.x & 63, wv = threadIdx.x >> 6;
    const int col = lane & 31, h = lane >> 5;
    const float16 z = zero16();

    // XCD-batch affinity: blk&7 is XCD slot; slot>=4 -> batch 1
    int slot = blockIdx.x & 7, batch = slot >> 2;
    int grp = (blockIdx.x >> 3) * 4 + (slot & 3);   // [0, 1024) within batch
    int base = batch * NPTS + grp * 64;             // 64 points per block

    // neighbor indices: 8 pairs per wave, preloaded (independent)
    int idxs[8];
#pragma unroll
    for (int it = 0; it < 8; it++)
        idxs[it] = nidx[(base + 2 * (wv * 8 + it)) * 16 + col];

    float T[9];
#pragma unroll
    for (int j = 0; j < 9; j++) T[j] = Tg[batch * 16 + j];
    float W1f[9], b1v[3];
#pragma unroll
    for (int j = 0; j < 9; j++) W1f[j] = W1[j] * s1[j % 3];
#pragma unroll
    for (int j = 0; j < 3; j++) b1v[j] = b1[j];

    float e[8];
    F8 w0, w1, w2, zf;
    zf.u.x = zf.u.y = zf.u.z = zf.u.w = 0u;
    float sc3 = s3[col];
#pragma unroll
    for (int j = 0; j < 8; j++) e[j] = W3[(8 * h + j) * 32 + col] * sc3;
    w0.u = pk8(e);
#pragma unroll
    for (int j = 0; j < 8; j++) e[j] = W3[(16 + 8 * h + j) * 32 + col] * sc3;
    w1.u = pk8(e);
    w2 = zf;
    if (h == 0) {
        float e2[8] = {0.f, 0.f, 0.f, 0.f, 0.f, 0.f, 0.f, 0.f};
#pragma unroll
        for (int j = 0; j < 3; j++) e2[j] = W3[(32 + j) * 32 + col] * sc3;
        w2.u = pk8(e2);
    }
    float b3v = b3[col];

    // gather loop, register double-buffered; f_xyz inline on h==0 lanes
    F8 na0, na1;
    float nx0 = 0.f, nx1 = 0.f, nx2 = 0.f;
    {
        size_t row = ((size_t)batch << 16) + (unsigned)idxs[0];
        const unsigned short* ap = t1a + row * 32;
        na0.u = *(const uint4*)(ap + 8 * h);
        na1.u = *(const uint4*)(ap + 16 + 8 * h);
        if (h == 0) {
            const float* nxp = xyz + row * 3;
            nx0 = nxp[0]; nx1 = nxp[1]; nx2 = nxp[2];
        }
    }
    for (int it = 0; it < 8; it++) {
        F8 ca0 = na0, ca1 = na1;
        float cx0 = nx0, cx1 = nx1, cx2 = nx2;
        if (it < 7) {
            size_t row = ((size_t)batch << 16) + (unsigned)idxs[it + 1];
            const unsigned short* ap = t1a + row * 32;
            na0.u = *(const uint4*)(ap + 8 * h);
            na1.u = *(const uint4*)(ap + 16 + 8 * h);
            if (h == 0) {
                const float* nxp = xyz + row * 3;
                nx0 = nxp[0]; nx1 = nxp[1]; nx2 = nxp[2];
            }
        }
        F8 ca2 = zf;
        if (h == 0) {
            float q0 = cx0 * T[0] + cx1 * T[3] + cx2 * T[6];
            float q1 = cx0 * T[1] + cx1 * T[4] + cx2 * T[7];
            float q2 = cx0 * T[2] + cx1 * T[5] + cx2 * T[8];
            float r0 = relu(q0 * W1f[0] + q1 * W1f[3] + q2 * W1f[6] + b1v[0]);
            float r1 = relu(q0 * W1f[1] + q1 * W1f[4] + q2 * W1f[7] + b1v[1]);
            float r2 = relu(q0 * W1f[2] + q1 * W1f[5] + q2 * W1f[8] + b1v[2]);
            ca2.u.x = pk2(r0, r1); ca2.u.y = pk2(r2, 0.f);
        }
        float16 acc = z;
        acc = __builtin_amdgcn_mfma_f32_32x32x16_bf16(ca0.s, w0.s, acc, 0, 0, 0);
        acc = __builtin_amdgcn_mfma_f32_32x32x16_bf16(ca1.s, w1.s, acc, 0, 0, 0);
        acc = __builtin_amdgcn_mfma_f32_32x32x16_bf16(ca2.s, w2.s, acc, 0, 0, 0);
        float vA = acc[0], vB = acc[8];
#pragma unroll
        for (int r = 1; r < 8; r++) { vA = fmaxf(vA, acc[r]); vB = fmaxf(vB, acc[8 + r]); }
        vA = fmaxf(vA, __shfl_xor(vA, 32));
        vB = fmaxf(vB, __shfl_xor(vB, 32));
        vA = relu(vA + b3v);
        vB = relu(vB + b3v);
        float val = h ? vB : vA;
        int pl = 2 * (wv * 8 + it) + h;              // local point [0,64)
        mld[pl * 36 + col] = f2bf(val);
    }
    __syncthreads();

    // output GEMM: waves 0,1 handle 32 points each
    if (wv < 2) {
        F8 aw[4];
        float sc4 = s4[col];
#pragma unroll
        for (int t = 0; t < 4; t++) {
#pragma unroll
            for (int j = 0; j < 8; j++) e[j] = W4[(16 * t + 8 * h + j) * 32 + col] * sc4;
            aw[t].u = pk8(e);
        }
        float b4v[16];
#pragma unroll
        for (int r = 0; r < 16; r++) b4v[r] = b4[(r & 3) + 8 * (r >> 2) + 4 * h];
        int p_loc = wv * 32 + col;
        int p = base + p_loc;
        const unsigned short* bp = t2 + (size_t)p * 32 + 8 * h;
        F8 xf0, xf1;
        xf0.u = *(const uint4*)(bp);
        xf1.u = *(const uint4*)(bp + 16);
        const unsigned short* mp = mld + p_loc * 36;
        uint2 q0 = *(const uint2*)(mp + 8 * h);
        uint2 q1 = *(const uint2*)(mp + 8 * h + 4);
        uint2 q2 = *(const uint2*)(mp + 16 + 8 * h);
        uint2 q3 = *(const uint2*)(mp + 16 + 8 * h + 4);
        F8 xm0, xm1;
        xm0.u.x = q0.x; xm0.u.y = q0.y; xm0.u.z = q1.x; xm0.u.w = q1.y;
        xm1.u.x = q2.x; xm1.u.y = q2.y; xm1.u.z = q3.x; xm1.u.w = q3.y;
        float16 acc = z;
        acc = __builtin_amdgcn_mfma_f32_32x32x16_bf16(aw[0].s, xf0.s, acc, 0, 0, 0);
        acc = __builtin_amdgcn_mfma_f32_32x32x16_bf16(aw[1].s, xf1.s, acc, 0, 0, 0);
        acc = __builtin_amdgcn_mfma_f32_32x32x16_bf16(aw[2].s, xm0.s, acc, 0, 0, 0);
        acc = __builtin_amdgcn_mfma_f32_32x32x16_bf16(aw[3].s, xm1.s, acc, 0, 0, 0);
        float* ob = out + (size_t)(batch * 32) * NPTS + (p & (NPTS - 1));
#pragma unroll
        for (int r = 0; r < 16; r++) {
            int o = (r & 3) + 8 * (r >> 2) + 4 * h;
            ob[(size_t)o * NPTS] = relu(acc[r] + b4v[r]);
        }
    }
}

extern "C" void kernel_launch(void* const* d_in, const int* in_sizes, int n_in,
                              void* d_out, int out_size, void* d_ws, size_t ws_size,
                              hipStream_t stream)
{
    const float* feature = (const float*)d_in[0];
    const float* xyz     = (const float*)d_in[1];
    const int*   nidx    = (const int*)d_in[2];
    const float* tW1 = (const float*)d_in[3];
    const float* ts1 = (const float*)d_in[4];
    const float* tb1 = (const float*)d_in[5];
    const float* tW2 = (const float*)d_in[6];
    const float* ts2 = (const float*)d_in[7];
    const float* tb2 = (const float*)d_in[8];
    const float* tW3 = (const float*)d_in[9];
    const float* ts3 = (const float*)d_in[10];
    const float* tb3 = (const float*)d_in[11];
    const float* tW4 = (const float*)d_in[12];
    const float* tb4 = (const float*)d_in[13];
    const float* W1  = (const float*)d_in[14];
    const float* s1  = (const float*)d_in[15];
    const float* b1  = (const float*)d_in[16];
    const float* W2  = (const float*)d_in[17];
    const float* s2  = (const float*)d_in[18];
    const float* b2  = (const float*)d_in[19];
    const float* W3  = (const float*)d_in[20];
    const float* s3  = (const float*)d_in[21];
    const float* b3  = (const float*)d_in[22];
    const float* W4  = (const float*)d_in[23];
    const float* s4  = (const float*)d_in[24];
    const float* b4  = (const float*)d_in[25];
    (void)in_sizes; (void)n_in; (void)out_size; (void)ws_size;

    char* wsp = (char*)d_ws;
    float* outp = (float*)d_out;

    kA<<<1024, 256, 0, stream>>>(feature, xyz, tW1, ts1, tb1, tW2, ts2, tb2,
                                 W2, s2, b2, wsp);
    kH<<<2, 256, 0, stream>>>(tW3, ts3, tb3, tW4, tb4, wsp);
    kB<<<2048, 256, 0, stream>>>(xyz, nidx, W1, s1, b1, W3, s3, b3, W4, s4, b4,
                                 wsp, outp);
}

// Round 10
// 165.569 us; speedup vs baseline: 1.1956x; 1.0723x over previous
//
#include <hip/hip_runtime.h>

#define NPTS   65536
#define TOTAL  (2 * NPTS)

typedef __attribute__((ext_vector_type(8)))  short short8;
typedef __attribute__((ext_vector_type(16))) float float16;
union F8 { uint4 u; short8 s; };

// ws byte offsets
#define WS_STRIPE 0                      // fp32[16][128] replica max stripe (memset 0)
#define WS_T1A    8192                   // bf16[TOTAL][32] f_nei, 64B rows
#define WS_T2     (8192 + TOTAL * 64)    // bf16[TOTAL][32] feat, 64B rows

__device__ __forceinline__ unsigned short f2bf(float x) {
    unsigned u = __float_as_uint(x);
    return (unsigned short)((u + 0x7FFFu + ((u >> 16) & 1u)) >> 16);
}
__device__ __forceinline__ unsigned pk2(float a, float b) {
    return (unsigned)f2bf(a) | ((unsigned)f2bf(b) << 16);
}
__device__ __forceinline__ float relu(float x) { return x > 0.f ? x : 0.f; }
__device__ __forceinline__ uint4 pk8(const float* e) {
    uint4 u;
    u.x = pk2(e[0], e[1]); u.y = pk2(e[2], e[3]);
    u.z = pk2(e[4], e[5]); u.w = pk2(e[6], e[7]);
    return u;
}
__device__ __forceinline__ float16 zero16() {
    float16 z;
#pragma unroll
    for (int i = 0; i < 16; i++) z[i] = 0.f;
    return z;
}

// ===== Kernel A: tnet trunk + block max -> replica-stripe atomicMax;
// =====           f_nei GEMM -> t1a; feat bf16 copy -> t2 =====
__global__ __launch_bounds__(256) void kA(
    const float* __restrict__ feature, const float* __restrict__ xyz,
    const float* __restrict__ tW1, const float* __restrict__ ts1, const float* __restrict__ tb1,
    const float* __restrict__ tW2, const float* __restrict__ ts2, const float* __restrict__ tb2,
    const float* __restrict__ W2,  const float* __restrict__ s2,  const float* __restrict__ b2,
    char* ws)
{
    __shared__ float red[4][64];
    float* stripe       = (float*)(ws + WS_STRIPE);
    unsigned short* t1a = (unsigned short*)(ws + WS_T1A);
    unsigned short* t2  = (unsigned short*)(ws + WS_T2);
    const int lane = threadIdx.x & 63, wv = threadIdx.x >> 6;
    const int col = lane & 31, h = lane >> 5;
    const float16 z = zero16();
    const int u = blockIdx.x;                   // 1024 blocks, 128 pts each
    const int b = u >> 9;
    float e[8];
    float aw0[8], aw1[8], aw2[8], bb[8];
#pragma unroll
    for (int j = 0; j < 8; j++) {
        int k = 8 * h + j; float s = ts1[k];
        aw0[j] = tW1[k] * s; aw1[j] = tW1[16 + k] * s; aw2[j] = tW1[32 + k] * s;
        bb[j] = tb1[k];
    }
    F8 bf0, bf1;
#pragma unroll
    for (int j = 0; j < 8; j++) e[j] = tW2[(8 * h + j) * 64 + col] * ts2[col];
    bf0.u = pk8(e);
#pragma unroll
    for (int j = 0; j < 8; j++) e[j] = tW2[(8 * h + j) * 64 + 32 + col] * ts2[32 + col];
    bf1.u = pk8(e);
    F8 a0, a1;
    float sc2 = s2[col];
#pragma unroll
    for (int j = 0; j < 8; j++) e[j] = W2[(8 * h + j) * 32 + col] * sc2;
    a0.u = pk8(e);
#pragma unroll
    for (int j = 0; j < 8; j++) e[j] = W2[(16 + 8 * h + j) * 32 + col] * sc2;
    a1.u = pk8(e);
    float b2v[16];
#pragma unroll
    for (int r = 0; r < 16; r++) b2v[r] = b2[(r & 3) + 8 * (r >> 2) + 4 * h];

    int base = u * 128 + wv * 32;
    const float* xp = xyz + (size_t)(base + col) * 3;
    float x0 = xp[0], x1 = xp[1], x2 = xp[2];
    float hv[8];
#pragma unroll
    for (int j = 0; j < 8; j++)
        hv[j] = relu(x0 * aw0[j] + x1 * aw1[j] + x2 * aw2[j] + bb[j]);
    F8 af; af.u = pk8(hv);
    float16 c0 = __builtin_amdgcn_mfma_f32_32x32x16_bf16(af.s, bf0.s, z, 0, 0, 0);
    float16 c1 = __builtin_amdgcn_mfma_f32_32x32x16_bf16(af.s, bf1.s, z, 0, 0, 0);
    float v0 = c0[0], v1 = c1[0];
#pragma unroll
    for (int i = 1; i < 16; i++) { v0 = fmaxf(v0, c0[i]); v1 = fmaxf(v1, c1[i]); }
    v0 = fmaxf(v0, __shfl_xor(v0, 32));
    v1 = fmaxf(v1, __shfl_xor(v1, 32));
    if (h == 0) { red[wv][col] = v0; red[wv][32 + col] = v1; }
    __syncthreads();
    if (threadIdx.x < 64) {
        int c = threadIdx.x;
        float m = fmaxf(fmaxf(red[0][c], red[1][c]), fmaxf(red[2][c], red[3][c]));
        float val = relu(m + tb2[c]);           // relu(x+tb) monotone: valid before global max
        atomicMax((unsigned*)(stripe + (u & 15) * 128 + b * 64 + c), __float_as_uint(val));
    }
    // f_nei GEMM + feat bf16 copy
    int pt = base + col;
    const float* fb = feature + (size_t)b * 32 * NPTS + (pt & (NPTS - 1));
    float v[8];
    F8 f0, f1;
#pragma unroll
    for (int j = 0; j < 8; j++) v[j] = fb[(size_t)(8 * h + j) * NPTS];
    f0.u = pk8(v);
#pragma unroll
    for (int j = 0; j < 8; j++) v[j] = fb[(size_t)(16 + 8 * h + j) * NPTS];
    f1.u = pk8(v);
    *(uint4*)(t2 + (size_t)pt * 32 + 8 * h) = f0.u;
    *(uint4*)(t2 + (size_t)pt * 32 + 16 + 8 * h) = f1.u;
    float16 acc = z;
    acc = __builtin_amdgcn_mfma_f32_32x32x16_bf16(a0.s, f0.s, acc, 0, 0, 0);
    acc = __builtin_amdgcn_mfma_f32_32x32x16_bf16(a1.s, f1.s, acc, 0, 0, 0);
#pragma unroll
    for (int q = 0; q < 4; q++) {
        int r = 4 * q;
        uint2 uu;
        uu.x = pk2(relu(acc[r] + b2v[r]), relu(acc[r + 1] + b2v[r + 1]));
        uu.y = pk2(relu(acc[r + 2] + b2v[r + 2]), relu(acc[r + 3] + b2v[r + 3]));
        *(uint2*)(t1a + (size_t)pt * 32 + 8 * q + 4 * h) = uu;
    }
}

// ===== Kernel B: per-wave tnet head (replica stripe) + gather GEMM (inline f_xyz)
// =====           + max-over-K + output GEMM =====
__global__ __launch_bounds__(256) void kB(
    const float* __restrict__ xyz, const int* __restrict__ nidx,
    const float* __restrict__ tW3, const float* __restrict__ ts3, const float* __restrict__ tb3,
    const float* __restrict__ tW4, const float* __restrict__ tb4,
    const float* __restrict__ W1,  const float* __restrict__ s1, const float* __restrict__ b1,
    const float* __restrict__ W3,  const float* __restrict__ s3, const float* __restrict__ b3,
    const float* __restrict__ W4,  const float* __restrict__ s4, const float* __restrict__ b4,
    char* ws, float* __restrict__ out)
{
    __shared__ unsigned short mld[64 * 36];
    const float* stripe       = (const float*)(ws + WS_STRIPE);
    const unsigned short* t1a = (const unsigned short*)(ws + WS_T1A);
    const unsigned short* t2  = (const unsigned short*)(ws + WS_T2);
    const int lane = threadIdx.x & 63, wv = threadIdx.x >> 6;
    const int col = lane & 31, h = lane >> 5;
    const float16 z = zero16();

    // XCD-batch affinity: blk&7 is XCD slot; slot>=4 -> batch 1
    int slot = blockIdx.x & 7, batch = slot >> 2;
    int grp = (blockIdx.x >> 3) * 4 + (slot & 3);   // [0, 1024) within batch
    int base = batch * NPTS + grp * 64;             // 64 points per block

    // neighbor indices: 8 pairs per wave, preloaded (independent, overlap head compute)
    int idxs[8];
#pragma unroll
    for (int it = 0; it < 8; it++)
        idxs[it] = nidx[(base + 2 * (wv * 8 + it)) * 16 + col];

    // per-wave tnet head from 16-replica stripe (4KB, L2-hot)
    float T[9];
    {
        float hm = 0.f;                             // relu'd values >= 0
#pragma unroll
        for (int s = 0; s < 16; s++)
            hm = fmaxf(hm, stripe[s * 128 + batch * 64 + lane]);
        float v[16];                                // lane i holds hm_i * tW3[i][:]
        const float4* trow = (const float4*)(tW3 + lane * 16);
#pragma unroll
        for (int q = 0; q < 4; q++) {
            float4 t4 = trow[q];
            v[4 * q + 0] = hm * t4.x; v[4 * q + 1] = hm * t4.y;
            v[4 * q + 2] = hm * t4.z; v[4 * q + 3] = hm * t4.w;
        }
#pragma unroll
        for (int off = 1; off < 64; off <<= 1) {
#pragma unroll
            for (int c = 0; c < 16; c++) v[c] += __shfl_xor(v[c], off);
        }
#pragma unroll
        for (int j = 0; j < 9; j++) T[j] = tb4[j];
#pragma unroll
        for (int c = 0; c < 16; c++) {
            float h3 = relu(v[c] * ts3[c] + tb3[c]);
#pragma unroll
            for (int j = 0; j < 9; j++) T[j] += h3 * tW4[c * 9 + j];
        }
        T[0] += 1.f; T[4] += 1.f; T[8] += 1.f;
    }
    float W1f[9], b1v[3];
#pragma unroll
    for (int j = 0; j < 9; j++) W1f[j] = W1[j] * s1[j % 3];
#pragma unroll
    for (int j = 0; j < 3; j++) b1v[j] = b1[j];

    float e[8];
    F8 w0, w1, w2, zf;
    zf.u.x = zf.u.y = zf.u.z = zf.u.w = 0u;
    float sc3 = s3[col];
#pragma unroll
    for (int j = 0; j < 8; j++) e[j] = W3[(8 * h + j) * 32 + col] * sc3;
    w0.u = pk8(e);
#pragma unroll
    for (int j = 0; j < 8; j++) e[j] = W3[(16 + 8 * h + j) * 32 + col] * sc3;
    w1.u = pk8(e);
    w2 = zf;
    if (h == 0) {
        float e2[8] = {0.f, 0.f, 0.f, 0.f, 0.f, 0.f, 0.f, 0.f};
#pragma unroll
        for (int j = 0; j < 3; j++) e2[j] = W3[(32 + j) * 32 + col] * sc3;
        w2.u = pk8(e2);
    }
    float b3v = b3[col];

    // gather loop, register double-buffered; f_xyz inline on h==0 lanes
    F8 na0, na1;
    float nx0 = 0.f, nx1 = 0.f, nx2 = 0.f;
    {
        size_t row = ((size_t)batch << 16) + (unsigned)idxs[0];
        const unsigned short* ap = t1a + row * 32;
        na0.u = *(const uint4*)(ap + 8 * h);
        na1.u = *(const uint4*)(ap + 16 + 8 * h);
        if (h == 0) {
            const float* nxp = xyz + row * 3;
            nx0 = nxp[0]; nx1 = nxp[1]; nx2 = nxp[2];
        }
    }
    for (int it = 0; it < 8; it++) {
        F8 ca0 = na0, ca1 = na1;
        float cx0 = nx0, cx1 = nx1, cx2 = nx2;
        if (it < 7) {
            size_t row = ((size_t)batch << 16) + (unsigned)idxs[it + 1];
            const unsigned short* ap = t1a + row * 32;
            na0.u = *(const uint4*)(ap + 8 * h);
            na1.u = *(const uint4*)(ap + 16 + 8 * h);
            if (h == 0) {
                const float* nxp = xyz + row * 3;
                nx0 = nxp[0]; nx1 = nxp[1]; nx2 = nxp[2];
            }
        }
        F8 ca2 = zf;
        if (h == 0) {
            float q0 = cx0 * T[0] + cx1 * T[3] + cx2 * T[6];
            float q1 = cx0 * T[1] + cx1 * T[4] + cx2 * T[7];
            float q2 = cx0 * T[2] + cx1 * T[5] + cx2 * T[8];
            float r0 = relu(q0 * W1f[0] + q1 * W1f[3] + q2 * W1f[6] + b1v[0]);
            float r1 = relu(q0 * W1f[1] + q1 * W1f[4] + q2 * W1f[7] + b1v[1]);
            float r2 = relu(q0 * W1f[2] + q1 * W1f[5] + q2 * W1f[8] + b1v[2]);
            ca2.u.x = pk2(r0, r1); ca2.u.y = pk2(r2, 0.f);
        }
        float16 acc = z;
        acc = __builtin_amdgcn_mfma_f32_32x32x16_bf16(ca0.s, w0.s, acc, 0, 0, 0);
        acc = __builtin_amdgcn_mfma_f32_32x32x16_bf16(ca1.s, w1.s, acc, 0, 0, 0);
        acc = __builtin_amdgcn_mfma_f32_32x32x16_bf16(ca2.s, w2.s, acc, 0, 0, 0);
        float vA = acc[0], vB = acc[8];
#pragma unroll
        for (int r = 1; r < 8; r++) { vA = fmaxf(vA, acc[r]); vB = fmaxf(vB, acc[8 + r]); }
        vA = fmaxf(vA, __shfl_xor(vA, 32));
        vB = fmaxf(vB, __shfl_xor(vB, 32));
        vA = relu(vA + b3v);
        vB = relu(vB + b3v);
        float val = h ? vB : vA;
        int pl = 2 * (wv * 8 + it) + h;              // local point [0,64)
        mld[pl * 36 + col] = f2bf(val);
    }
    __syncthreads();

    // output GEMM: waves 0,1 handle 32 points each
    if (wv < 2) {
        F8 aw[4];
        float sc4 = s4[col];
#pragma unroll
        for (int t = 0; t < 4; t++) {
#pragma unroll
            for (int j = 0; j < 8; j++) e[j] = W4[(16 * t + 8 * h + j) * 32 + col] * sc4;
            aw[t].u = pk8(e);
        }
        float b4v[16];
#pragma unroll
        for (int r = 0; r < 16; r++) b4v[r] = b4[(r & 3) + 8 * (r >> 2) + 4 * h];
        int p_loc = wv * 32 + col;
        int p = base + p_loc;
        const unsigned short* bp = t2 + (size_t)p * 32 + 8 * h;
        F8 xf0, xf1;
        xf0.u = *(const uint4*)(bp);
        xf1.u = *(const uint4*)(bp + 16);
        const unsigned short* mp = mld + p_loc * 36;
        uint2 q0 = *(const uint2*)(mp + 8 * h);
        uint2 q1 = *(const uint2*)(mp + 8 * h + 4);
        uint2 q2 = *(const uint2*)(mp + 16 + 8 * h);
        uint2 q3 = *(const uint2*)(mp + 16 + 8 * h + 4);
        F8 xm0, xm1;
        xm0.u.x = q0.x; xm0.u.y = q0.y; xm0.u.z = q1.x; xm0.u.w = q1.y;
        xm1.u.x = q2.x; xm1.u.y = q2.y; xm1.u.z = q3.x; xm1.u.w = q3.y;
        float16 acc = z;
        acc = __builtin_amdgcn_mfma_f32_32x32x16_bf16(aw[0].s, xf0.s, acc, 0, 0, 0);
        acc = __builtin_amdgcn_mfma_f32_32x32x16_bf16(aw[1].s, xf1.s, acc, 0, 0, 0);
        acc = __builtin_amdgcn_mfma_f32_32x32x16_bf16(aw[2].s, xm0.s, acc, 0, 0, 0);
        acc = __builtin_amdgcn_mfma_f32_32x32x16_bf16(aw[3].s, xm1.s, acc, 0, 0, 0);
        float* ob = out + (size_t)(batch * 32) * NPTS + (p & (NPTS - 1));
#pragma unroll
        for (int r = 0; r < 16; r++) {
            int o = (r & 3) + 8 * (r >> 2) + 4 * h;
            ob[(size_t)o * NPTS] = relu(acc[r] + b4v[r]);
        }
    }
}

extern "C" void kernel_launch(void* const* d_in, const int* in_sizes, int n_in,
                              void* d_out, int out_size, void* d_ws, size_t ws_size,
                              hipStream_t stream)
{
    const float* feature = (const float*)d_in[0];
    const float* xyz     = (const float*)d_in[1];
    const int*   nidx    = (const int*)d_in[2];
    const float* tW1 = (const float*)d_in[3];
    const float* ts1 = (const float*)d_in[4];
    const float* tb1 = (const float*)d_in[5];
    const float* tW2 = (const float*)d_in[6];
    const float* ts2 = (const float*)d_in[7];
    const float* tb2 = (const float*)d_in[8];
    const float* tW3 = (const float*)d_in[9];
    const float* ts3 = (const float*)d_in[10];
    const float* tb3 = (const float*)d_in[11];
    const float* tW4 = (const float*)d_in[12];
    const float* tb4 = (const float*)d_in[13];
    const float* W1  = (const float*)d_in[14];
    const float* s1  = (const float*)d_in[15];
    const float* b1  = (const float*)d_in[16];
    const float* W2  = (const float*)d_in[17];
    const float* s2  = (const float*)d_in[18];
    const float* b2  = (const float*)d_in[19];
    const float* W3  = (const float*)d_in[20];
    const float* s3  = (const float*)d_in[21];
    const float* b3  = (const float*)d_in[22];
    const float* W4  = (const float*)d_in[23];
    const float* s4  = (const float*)d_in[24];
    const float* b4  = (const float*)d_in[25];
    (void)in_sizes; (void)n_in; (void)out_size; (void)ws_size;

    char* wsp = (char*)d_ws;
    float* outp = (float*)d_out;

    hipMemsetAsync(wsp + WS_STRIPE, 0, 16 * 128 * sizeof(float), stream);
    kA<<<1024, 256, 0, stream>>>(feature, xyz, tW1, ts1, tb1, tW2, ts2, tb2,
                                 W2, s2, b2, wsp);
    kB<<<2048, 256, 0, stream>>>(xyz, nidx, tW3, ts3, tb3, tW4, tb4,
                                 W1, s1, b1, W3, s3, b3, W4, s4, b4, wsp, outp);
}